// Round 11
// baseline (5297.448 us; speedup 1.0000x reference)
//
#include <hip/hip_runtime.h>

#define NB 128      // batch
#define NT 8192     // time steps
#define NS 128      // states
#define NE 6        // alphabet
#define ROWS2 32    // batch rows per block = 2 chains x 16
#define WAVES 8     // 512 threads; wave w owns STATES [16w, 16w+16)
#define NMAT 7      // C_0..C_5 = A*diag(e_o)*A (bf16), C_6 = A (bf16)
#define CT_BYTES (NMAT * NS * NS * 2)    // 229376

typedef __attribute__((ext_vector_type(8))) short bf16x8;   // 8 bf16 (4 VGPRs)
typedef __attribute__((ext_vector_type(4))) float f32x4;    // MFMA accumulator
typedef __attribute__((ext_vector_type(4))) int   int32x4;

#define MFMA __builtin_amdgcn_mfma_f32_16x16x32_bf16

// fp32 -> bf16, round-to-nearest-even
__device__ __forceinline__ ushort f2bf(float v) {
    unsigned u = __float_as_uint(v);
    u += 0x7fffu + ((u >> 16) & 1u);
    return (ushort)(u >> 16);
}

// XOR swizzle for alpha LDS (bf16 elems): breaks stride-256B bank conflicts,
// preserves 16B alignment of the b128 A-fragment reads (k-offsets 8-aligned).
#define SWZ(r, c) ((((r) * NS) + (c)) ^ (((r) & 7) << 3))

// ---------------------------------------------------------------------------
// Precompute Ct (bf16, transposed: Ct[(m*NS + col)*NS + k] = C_m[k][col]).
// C_m = A * diag(Bm[:,m]) * A for m<6;  C_6 = A.  Grid (7, 4) x 128 threads.
// ---------------------------------------------------------------------------
__global__ void __launch_bounds__(128, 1)
hmm_precompute_kernel(const float* __restrict__ A, const float* __restrict__ Bm,
                      ushort* __restrict__ Ct)
{
    __shared__ float Af[NS * NS];   // 64 KB
    __shared__ float wA[NS * NS];   // 64 KB
    const int s  = threadIdx.x;
    const int m  = blockIdx.x;
    const int ig = blockIdx.y;      // k-row group [ig*32, ig*32+32)

    for (int r = 0; r < NS; ++r) Af[r * NS + s] = A[r * NS + s];
    __syncthreads();

    if (m < 6) {
        for (int k = 0; k < NS; ++k)
            wA[k * NS + s] = Bm[k * NE + m] * Af[k * NS + s];
        __syncthreads();
        for (int i0 = ig * 32; i0 < ig * 32 + 32; i0 += 4) {
            float a0 = 0.f, a1 = 0.f, a2 = 0.f, a3 = 0.f;
            for (int k = 0; k < NS; ++k) {
                const float wv = wA[k * NS + s];
                a0 = fmaf(Af[(i0 + 0) * NS + k], wv, a0);
                a1 = fmaf(Af[(i0 + 1) * NS + k], wv, a1);
                a2 = fmaf(Af[(i0 + 2) * NS + k], wv, a2);
                a3 = fmaf(Af[(i0 + 3) * NS + k], wv, a3);
            }
            Ct[(m * NS + s) * NS + i0 + 0] = f2bf(a0);
            Ct[(m * NS + s) * NS + i0 + 1] = f2bf(a1);
            Ct[(m * NS + s) * NS + i0 + 2] = f2bf(a2);
            Ct[(m * NS + s) * NS + i0 + 3] = f2bf(a3);
        }
    } else {
        for (int i = ig * 32; i < ig * 32 + 32; ++i)
            Ct[(6 * NS + s) * NS + i] = f2bf(Af[i * NS + s]);
    }
}

// ---------------------------------------------------------------------------
// Dual-chain pair-step kernel: one block = TWO independent 16-row chains.
// Per iteration = one pair-step for EACH chain, ONE barrier, double-buffered
// alpha per chain. The two chains' ds_reads / MFMAs / selects are mutually
// independent -> phases overlap instead of serializing in lockstep.
// ---------------------------------------------------------------------------
__global__ void __launch_bounds__(512, 2)
hmm_dual_kernel(const int* __restrict__ obs, const float* __restrict__ I,
                const float* __restrict__ Bm, const ushort* __restrict__ Ct,
                float* __restrict__ out)
{
    __shared__ __align__(16) ushort aldsA[2][16 * NS];   // chain A alpha (dbuf)
    __shared__ __align__(16) ushort aldsB[2][16 * NS];   // chain B alpha (dbuf)
    __shared__ float Bt[NE * NS];                        // emissions transposed
    __shared__ __align__(16) int obs_lds[ROWS2][132];    // 129 used (+overlap)
    __shared__ float partA[WAVES][16], partB[WAVES][16];
    __shared__ float ZsA[16], ZsB[16];

    const int tid = threadIdx.x;
    const int w   = tid >> 6;       // wave -> states [16w, 16w+16)
    const int l   = tid & 63;
    const int h   = l >> 4;         // quarter-wave
    const int li  = l & 15;
    const int cc  = 16 * w + li;    // this lane's output state column
    const int brow0 = blockIdx.x * ROWS2;

    // ---- B-fragments for the 6 pair matrices (shared by both chains) ----
    bf16x8 bfrag[6][4];
#pragma unroll
    for (int s = 0; s < 6; ++s)
#pragma unroll
        for (int q = 0; q < 4; ++q)
            bfrag[s][q] = *(const bf16x8*)(Ct + ((s * NS + cc) * NS + 32 * q + 8 * h));

    // ---- stage Bt ----
    if (tid < NS) {
#pragma unroll
        for (int k = 0; k < NE; ++k) Bt[k * NS + tid] = Bm[tid * NE + k];
    }
    // ---- stage obs chunk 0 (+ overlap entry 128) ----
    {
        const int b = tid >> 4, ii = (tid & 15) * 8;
        const int32x4* g = (const int32x4*)(obs + (size_t)(brow0 + b) * NT + ii);
        *(int32x4*)&obs_lds[b][ii]     = g[0];
        *(int32x4*)&obs_lds[b][ii + 4] = g[1];
        if (tid < ROWS2)
            obs_lds[tid][128] = obs[(size_t)(brow0 + tid) * NT + 128];
    }
    __syncthreads();

    // ---- t = 0: alpha = I * em_0 (unnormalized), both chains ----
    {
        const int b = tid >> 4, s0 = (tid & 15) * 8;
        const int o0 = obs_lds[b][0];
#pragma unroll
        for (int j = 0; j < 8; ++j) {
            const int c = s0 + j;
            const ushort v = f2bf(I[c] * Bt[o0 * NS + c]);
            if (b < 16) aldsA[0][SWZ(b, c)] = v;
            else        aldsB[0][SWZ(b - 16, c)] = v;
        }
    }
    __syncthreads();

    float llA = 0.f, llB = 0.f;   // llA valid on tid<16, llB on tid in [16,32)
    int   cur = 0;
    int   ps  = 0;                // pair counter (rescale every 16 pairs)

    for (int c = 0; c < 64; ++c) {
        if (c) {   // stage next chunk: t in [128c, 128c+128]
            const int b = tid >> 4, ii = (tid & 15) * 8;
            const int32x4* g =
                (const int32x4*)(obs + (size_t)(brow0 + b) * NT + 128 * c + ii);
            *(int32x4*)&obs_lds[b][ii]     = g[0];
            *(int32x4*)&obs_lds[b][ii + 4] = g[1];
            if (tid < ROWS2) {
                const int gi = 128 * c + 128;
                obs_lds[tid][128] = (gi < NT)
                    ? obs[(size_t)(brow0 + tid) * NT + gi] : 0;
            }
            __syncthreads();
        }
        const int npairs = (c < 63) ? 64 : 63;   // chunk 63: 63 pairs + final single
        for (int p = 0; p < npairs; ++p) {
            const int i1 = 2 * p + 1;

            // ---- issue both chains' alpha-fragment reads up front ----
            bf16x8 af0[4], af1[4];
#pragma unroll
            for (int q = 0; q < 4; ++q) {
                af0[q] = *(const bf16x8*)&aldsA[cur][SWZ(li, 32 * q + 8 * h)];
                af1[q] = *(const bf16x8*)&aldsB[cur][SWZ(li, 32 * q + 8 * h)];
            }
            // ---- symbol reads (independent of alpha, overlap MFMA) ----
            int o1A[4], o2A[4], o1B[4], o2B[4];
#pragma unroll
            for (int r = 0; r < 4; ++r) {
                const int row = 4 * h + r;
                o1A[r] = obs_lds[row][i1];      o2A[r] = obs_lds[row][i1 + 1];
                o1B[r] = obs_lds[16 + row][i1]; o2B[r] = obs_lds[16 + row][i1 + 1];
            }

            // ---- 48 MFMAs: 12 independent accumulator chains of depth 4 ----
            f32x4 acc0[6], acc1[6];
#pragma unroll
            for (int s = 0; s < 6; ++s) {
                acc0[s] = (f32x4){0.f, 0.f, 0.f, 0.f};
                acc1[s] = (f32x4){0.f, 0.f, 0.f, 0.f};
            }
#pragma unroll
            for (int q = 0; q < 4; ++q)
#pragma unroll
                for (int s = 0; s < 6; ++s) {
                    acc0[s] = MFMA(af0[q], bfrag[s][q], acc0[s], 0, 0, 0);
                    acc1[s] = MFMA(af1[q], bfrag[s][q], acc1[s], 0, 0, 0);
                }

            // ---- select by o1, apply emission e_{o2}[cc] via Bt gather ----
            float vA[4], vB[4];
#pragma unroll
            for (int r = 0; r < 4; ++r) {
                int s1 = o1A[r];
                float v = acc0[0][r];
                v = (s1 == 1) ? acc0[1][r] : v;
                v = (s1 == 2) ? acc0[2][r] : v;
                v = (s1 == 3) ? acc0[3][r] : v;
                v = (s1 == 4) ? acc0[4][r] : v;
                v = (s1 == 5) ? acc0[5][r] : v;
                vA[r] = v * Bt[o2A[r] * NS + cc];

                s1 = o1B[r];
                v = acc1[0][r];
                v = (s1 == 1) ? acc1[1][r] : v;
                v = (s1 == 2) ? acc1[2][r] : v;
                v = (s1 == 3) ? acc1[3][r] : v;
                v = (s1 == 4) ? acc1[4][r] : v;
                v = (s1 == 5) ? acc1[5][r] : v;
                vB[r] = v * Bt[o2B[r] * NS + cc];
            }

            ++ps;
            if ((ps & 15) == 0) {   // rescale both chains (block-uniform)
#pragma unroll
                for (int r = 0; r < 4; ++r) {
                    float sA = vA[r], sB = vB[r];
#pragma unroll
                    for (int off = 1; off < 16; off <<= 1) {
                        sA += __shfl_xor(sA, off);
                        sB += __shfl_xor(sB, off);
                    }
                    if (li == 0) { partA[w][4 * h + r] = sA; partB[w][4 * h + r] = sB; }
                }
                __syncthreads();
                if (tid < 16) {
                    float Z = 0.f;
#pragma unroll
                    for (int ww = 0; ww < WAVES; ++ww) Z += partA[ww][tid];
                    llA += logf(Z);
                    ZsA[tid] = 1.0f / Z;
                } else if (tid < 32) {
                    const int t2 = tid - 16;
                    float Z = 0.f;
#pragma unroll
                    for (int ww = 0; ww < WAVES; ++ww) Z += partB[ww][t2];
                    llB += logf(Z);
                    ZsB[t2] = 1.0f / Z;
                }
                __syncthreads();
#pragma unroll
                for (int r = 0; r < 4; ++r) {
                    vA[r] *= ZsA[4 * h + r];
                    vB[r] *= ZsB[4 * h + r];
                }
            }

            // ---- write both chains' new alpha (swizzled bf16) ----
#pragma unroll
            for (int r = 0; r < 4; ++r) {
                aldsA[cur ^ 1][SWZ(4 * h + r, cc)] = f2bf(vA[r]);
                aldsB[cur ^ 1][SWZ(4 * h + r, cc)] = f2bf(vB[r]);
            }
            __syncthreads();
            cur ^= 1;
        }
    }

    // ---- final single step t = 8191: alpha @ A (Ct[6]), * e, both chains ----
    {
        bf16x8 af0[4], af1[4], afin[4];
#pragma unroll
        for (int q = 0; q < 4; ++q) {
            afin[q] = *(const bf16x8*)(Ct + ((6 * NS + cc) * NS + 32 * q + 8 * h));
            af0[q]  = *(const bf16x8*)&aldsA[cur][SWZ(li, 32 * q + 8 * h)];
            af1[q]  = *(const bf16x8*)&aldsB[cur][SWZ(li, 32 * q + 8 * h)];
        }
        f32x4 a0 = (f32x4){0.f, 0.f, 0.f, 0.f};
        f32x4 a1 = (f32x4){0.f, 0.f, 0.f, 0.f};
#pragma unroll
        for (int q = 0; q < 4; ++q) {
            a0 = MFMA(af0[q], afin[q], a0, 0, 0, 0);
            a1 = MFMA(af1[q], afin[q], a1, 0, 0, 0);
        }
#pragma unroll
        for (int r = 0; r < 4; ++r) {
            const int row = 4 * h + r;
            float sA = a0[r] * Bt[obs_lds[row][127] * NS + cc];
            float sB = a1[r] * Bt[obs_lds[16 + row][127] * NS + cc];
#pragma unroll
            for (int off = 1; off < 16; off <<= 1) {
                sA += __shfl_xor(sA, off);
                sB += __shfl_xor(sB, off);
            }
            if (li == 0) { partA[w][row] = sA; partB[w][row] = sB; }
        }
        __syncthreads();
        if (tid < 16) {
            float Z = 0.f;
#pragma unroll
            for (int ww = 0; ww < WAVES; ++ww) Z += partA[ww][tid];
            out[brow0 + tid] = llA + logf(Z);
        } else if (tid < 32) {
            const int t2 = tid - 16;
            float Z = 0.f;
#pragma unroll
            for (int ww = 0; ww < WAVES; ++ww) Z += partB[ww][t2];
            out[brow0 + tid] = llB + logf(Z);
        }
    }
}

// ---------------------------------------------------------------------------
// Fallback (round-7 kernel) if workspace is too small for Ct.
// ---------------------------------------------------------------------------
__global__ void __launch_bounds__(256, 1)
hmm_gemm_kernel(const int* __restrict__ obs, const float* __restrict__ I,
                const float* __restrict__ A, const float* __restrict__ Bm,
                float* __restrict__ out)
{
    __shared__ __align__(16) ushort alds2[2][16 * NS];
    __shared__ float Bt[NE * NS];
    __shared__ __align__(16) int obs_lds[16][132];
    __shared__ float part[4][16];
    __shared__ float Zs[16];

    const int tid = threadIdx.x;
    const int w   = tid >> 6;
    const int l   = tid & 63;
    const int h   = l >> 4;
    const int li  = l & 15;
    const int brow0 = blockIdx.x * 16;

    if (tid < NS) {
#pragma unroll
        for (int k = 0; k < NE; ++k) Bt[k * NS + tid] = Bm[tid * NE + k];
    }
    {
        const int r = tid >> 4, i0 = (tid & 15) * 8;
        const int32x4* g = (const int32x4*)(obs + (size_t)(brow0 + r) * NT + i0);
        *(int32x4*)&obs_lds[r][i0]     = g[0];
        *(int32x4*)&obs_lds[r][i0 + 4] = g[1];
    }
    bf16x8 bfrag[2][4];
#pragma unroll
    for (int tl = 0; tl < 2; ++tl) {
#pragma unroll
        for (int q = 0; q < 4; ++q) {
            const float* src = A + (size_t)(32 * q + 8 * h) * NS + (32 * w + 16 * tl + li);
            bf16x8 f;
#pragma unroll
            for (int j = 0; j < 8; ++j) f[j] = (short)f2bf(src[j * NS]);
            bfrag[tl][q] = f;
        }
    }
    __syncthreads();
    {
        const int r = tid >> 4, c0 = (tid & 15) * 8;
        const int o0 = obs_lds[r][0];
#pragma unroll
        for (int j = 0; j < 8; ++j) {
            const int c = c0 + j;
            alds2[0][SWZ(r, c)] = f2bf(I[c] * Bt[o0 * NS + c]);
        }
    }
    __syncthreads();

    float ll = 0.f;
    int cur = 0;
    for (int t = 1; t < NT; ++t) {
        if ((t & 127) == 0) {
            const int r = tid >> 4, i0 = (tid & 15) * 8;
            const int32x4* g = (const int32x4*)(obs + (size_t)(brow0 + r) * NT + t + i0);
            *(int32x4*)&obs_lds[r][i0]     = g[0];
            *(int32x4*)&obs_lds[r][i0 + 4] = g[1];
            __syncthreads();
        }
        bf16x8 af[4];
#pragma unroll
        for (int q = 0; q < 4; ++q)
            af[q] = *(const bf16x8*)&alds2[cur][SWZ(li, 32 * q + 8 * h)];
        const int tt = t & 127;
        int o[4];
#pragma unroll
        for (int r = 0; r < 4; ++r) o[r] = obs_lds[4 * h + r][tt];
        f32x4 acc[2];
        acc[0] = (f32x4){0.f, 0.f, 0.f, 0.f};
        acc[1] = (f32x4){0.f, 0.f, 0.f, 0.f};
#pragma unroll
        for (int q = 0; q < 4; ++q) {
            acc[0] = MFMA(af[q], bfrag[0][q], acc[0], 0, 0, 0);
            acc[1] = MFMA(af[q], bfrag[1][q], acc[1], 0, 0, 0);
        }
        float vals[2][4];
#pragma unroll
        for (int tl = 0; tl < 2; ++tl) {
            const int cidx = 32 * w + 16 * tl + li;
#pragma unroll
            for (int r = 0; r < 4; ++r) vals[tl][r] = acc[tl][r] * Bt[o[r] * NS + cidx];
        }
        const bool resc = ((t & 15) == 0) || (t == NT - 1);
        if (resc) {
#pragma unroll
            for (int r = 0; r < 4; ++r) {
                float s = vals[0][r] + vals[1][r];
#pragma unroll
                for (int off = 1; off < 16; off <<= 1) s += __shfl_xor(s, off);
                if (li == 0) part[w][4 * h + r] = s;
            }
            __syncthreads();
            if (tid < 16) {
                float Z = part[0][tid] + part[1][tid] + part[2][tid] + part[3][tid];
                ll += logf(Z);
                Zs[tid] = 1.0f / Z;
            }
            __syncthreads();
#pragma unroll
            for (int tl = 0; tl < 2; ++tl)
#pragma unroll
                for (int r = 0; r < 4; ++r) vals[tl][r] *= Zs[4 * h + r];
        }
#pragma unroll
        for (int tl = 0; tl < 2; ++tl) {
            const int cidx = 32 * w + 16 * tl + li;
#pragma unroll
            for (int r = 0; r < 4; ++r)
                alds2[cur ^ 1][SWZ(4 * h + r, cidx)] = f2bf(vals[tl][r]);
        }
        __syncthreads();
        cur ^= 1;
    }
    if (tid < 16) out[brow0 + tid] = ll;
}

extern "C" void kernel_launch(void* const* d_in, const int* in_sizes, int n_in,
                              void* d_out, int out_size, void* d_ws, size_t ws_size,
                              hipStream_t stream) {
    (void)in_sizes; (void)n_in; (void)out_size;
    const int*   obs = (const int*)d_in[0];
    const float* I   = (const float*)d_in[1];
    const float* A   = (const float*)d_in[2];
    const float* Bm  = (const float*)d_in[3];
    float*       out = (float*)d_out;

    if (ws_size < (size_t)CT_BYTES) {
        hipLaunchKernelGGL(hmm_gemm_kernel, dim3(NB / 16), dim3(256), 0, stream,
                           obs, I, A, Bm, out);
        return;
    }
    ushort* Ct = (ushort*)d_ws;
    hipLaunchKernelGGL(hmm_precompute_kernel, dim3(NMAT, 4), dim3(128), 0, stream,
                       A, Bm, Ct);
    hipLaunchKernelGGL(hmm_dual_kernel, dim3(NB / ROWS2), dim3(512), 0, stream,
                       obs, I, Bm, Ct, out);
}

// Round 12
// 3121.907 us; speedup vs baseline: 1.6969x; 1.6969x over previous
//
#include <hip/hip_runtime.h>

#define NB 128      // batch
#define NT 8192     // time steps
#define NS 128      // states
#define NE 6        // alphabet
#define ROWS 16     // batch rows per block
#define WAVES 8     // 512 threads; wave w owns STATES [16w, 16w+16)
#define NMAT 7      // C_0..C_5 = A*diag(e_o)*A (bf16), C_6 = A (bf16)
#define CT_BYTES (NMAT * NS * NS * 2)    // 229376

typedef __attribute__((ext_vector_type(8))) short bf16x8;   // 8 bf16 (4 VGPRs)
typedef __attribute__((ext_vector_type(4))) float f32x4;    // MFMA accumulator
typedef __attribute__((ext_vector_type(4))) int   int32x4;

#define MFMA __builtin_amdgcn_mfma_f32_16x16x32_bf16

// fp32 -> bf16, round-to-nearest-even
__device__ __forceinline__ ushort f2bf(float v) {
    unsigned u = __float_as_uint(v);
    u += 0x7fffu + ((u >> 16) & 1u);
    return (ushort)(u >> 16);
}

// XOR swizzle for alpha LDS (bf16 elems): breaks stride-256B bank conflicts,
// preserves 16B alignment of the b128 A-fragment reads (k-offsets 8-aligned).
#define SWZ(r, c) ((((r) * NS) + (c)) ^ (((r) & 7) << 3))

// ---------------------------------------------------------------------------
// Precompute Ct (bf16, transposed: Ct[(m*NS + col)*NS + k] = C_m[k][col]).
// C_m = A * diag(Bm[:,m]) * A for m<6;  C_6 = A.  Grid (7, 4) x 128 threads.
// ---------------------------------------------------------------------------
__global__ void __launch_bounds__(128, 1)
hmm_precompute_kernel(const float* __restrict__ A, const float* __restrict__ Bm,
                      ushort* __restrict__ Ct)
{
    __shared__ float Af[NS * NS];   // 64 KB
    __shared__ float wA[NS * NS];   // 64 KB
    const int s  = threadIdx.x;
    const int m  = blockIdx.x;
    const int ig = blockIdx.y;      // k-row group [ig*32, ig*32+32)

    for (int r = 0; r < NS; ++r) Af[r * NS + s] = A[r * NS + s];
    __syncthreads();

    if (m < 6) {
        for (int k = 0; k < NS; ++k)
            wA[k * NS + s] = Bm[k * NE + m] * Af[k * NS + s];
        __syncthreads();
        for (int i0 = ig * 32; i0 < ig * 32 + 32; i0 += 4) {
            float a0 = 0.f, a1 = 0.f, a2 = 0.f, a3 = 0.f;
            for (int k = 0; k < NS; ++k) {
                const float wv = wA[k * NS + s];
                a0 = fmaf(Af[(i0 + 0) * NS + k], wv, a0);
                a1 = fmaf(Af[(i0 + 1) * NS + k], wv, a1);
                a2 = fmaf(Af[(i0 + 2) * NS + k], wv, a2);
                a3 = fmaf(Af[(i0 + 3) * NS + k], wv, a3);
            }
            Ct[(m * NS + s) * NS + i0 + 0] = f2bf(a0);
            Ct[(m * NS + s) * NS + i0 + 1] = f2bf(a1);
            Ct[(m * NS + s) * NS + i0 + 2] = f2bf(a2);
            Ct[(m * NS + s) * NS + i0 + 3] = f2bf(a3);
        }
    } else {
        for (int i = ig * 32; i < ig * 32 + 32; ++i)
            Ct[(6 * NS + s) * NS + i] = f2bf(Af[i * NS + s]);
    }
}

// ---------------------------------------------------------------------------
// Pair-step kernel = the R8 winner + packed selectors (pk_lds).
// Per pair, per wave: 4 ds_read_b128 (alpha) + 1 broadcast u32 (selectors)
// + 4 Bt gathers + 4 b16 writes.  Select/emission epilogue identical to R8.
// 512 threads (8 waves), 16 batch rows per block, grid = 8.
// ---------------------------------------------------------------------------
__global__ void __launch_bounds__(512, 2)
hmm_pair8_kernel(const int* __restrict__ obs, const float* __restrict__ I,
                 const float* __restrict__ Bm, const ushort* __restrict__ Ct,
                 float* __restrict__ out)
{
    __shared__ __align__(16) ushort alds[2][ROWS * NS];  // bf16 alpha, dbuf, swizzled
    __shared__ float Bt[NE * NS];                        // emissions transposed
    __shared__ __align__(16) int obs_lds[ROWS][132];     // 129 entries used (+overlap)
    __shared__ unsigned pk_lds[64 * 4];                  // (o1|o2<<4) x 4 rows per (pair,h)
    __shared__ float part[WAVES][ROWS];                  // per-wave state partials
    __shared__ float Zs[ROWS];                           // 1/Z per batch row

    const int tid = threadIdx.x;
    const int w   = tid >> 6;       // wave -> states [16w, 16w+16)
    const int l   = tid & 63;
    const int h   = l >> 4;         // quarter-wave
    const int li  = l & 15;
    const int cc  = 16 * w + li;    // this lane's output state column
    const int brow0 = blockIdx.x * ROWS;

    // ---- B-fragments for the 6 pair matrices ----
    // bfrag[s][q] elem j = C_s[k = 32q + 8h + j][col = cc]
    bf16x8 bfrag[6][4];
#pragma unroll
    for (int s = 0; s < 6; ++s)
#pragma unroll
        for (int q = 0; q < 4; ++q)
            bfrag[s][q] = *(const bf16x8*)(Ct + ((s * NS + cc) * NS + 32 * q + 8 * h));
    bf16x8 afinB[4];   // plain A, for the final odd step
#pragma unroll
    for (int q = 0; q < 4; ++q)
        afinB[q] = *(const bf16x8*)(Ct + ((6 * NS + cc) * NS + 32 * q + 8 * h));

    // ---- stage Bt: Bt[o*NS + s] = Bm[s*NE + o] ----
    if (tid < NS) {
#pragma unroll
        for (int k = 0; k < NE; ++k) Bt[k * NS + tid] = Bm[tid * NE + k];
    }
    // ---- stage obs chunk 0 (+ overlap entry 128) ----
    {
        const int b = tid >> 5, ii = (tid & 31) * 4;
        *(int32x4*)&obs_lds[b][ii] =
            *(const int32x4*)(obs + (size_t)(brow0 + b) * NT + ii);
        if (tid < ROWS)
            obs_lds[tid][128] = obs[(size_t)(brow0 + tid) * NT + 128];
    }
    __syncthreads();

    // ---- t = 0: alpha = I * em_0 (unnormalized) ----
    {
        const int b = tid >> 5, s0 = (tid & 31) * 4;
        const int o0 = obs_lds[b][0];
#pragma unroll
        for (int j = 0; j < 4; ++j) {
            const int c = s0 + j;
            alds[0][SWZ(b, c)] = f2bf(I[c] * Bt[o0 * NS + c]);
        }
    }
    __syncthreads();

    float ll  = 0.f;   // valid on tid < ROWS (batch row = tid)
    int   cur = 0;
    int   ps  = 0;     // pair counter (rescale every 16 pairs = 32 steps)

    for (int c = 0; c < 64; ++c) {
        if (c) {   // stage next chunk: t in [128c, 128c+128]
            const int b = tid >> 5, ii = (tid & 31) * 4;
            *(int32x4*)&obs_lds[b][ii] =
                *(const int32x4*)(obs + (size_t)(brow0 + b) * NT + 128 * c + ii);
            if (tid < ROWS) {
                const int gi = 128 * c + 128;
                obs_lds[tid][128] = (gi < NT)
                    ? obs[(size_t)(brow0 + tid) * NT + gi] : 0;
            }
            __syncthreads();
        }
        // build packed selectors: pk_lds[p*4+hh] byte r = o1 | o2<<4 of row 4hh+r
        if (tid < 256) {
            const int p = tid >> 2, hh = tid & 3;
            unsigned pk = 0;
#pragma unroll
            for (int r = 0; r < 4; ++r) {
                const int o1 = obs_lds[4 * hh + r][2 * p + 1];
                const int o2 = obs_lds[4 * hh + r][2 * p + 2];
                pk |= (unsigned)(o1 | (o2 << 4)) << (8 * r);
            }
            pk_lds[p * 4 + hh] = pk;
        }
        __syncthreads();

        const int npairs = (c < 63) ? 64 : 63;   // chunk 63: 63 pairs + final single
        for (int p = 0; p < npairs; ++p) {
            // A-operand: alpha rows = batch li, k = 32q + 8h + j
            bf16x8 af[4];
#pragma unroll
            for (int q = 0; q < 4; ++q)
                af[q] = *(const bf16x8*)&alds[cur][SWZ(li, 32 * q + 8 * h)];

            const unsigned pk = pk_lds[p * 4 + h];   // broadcast within quarter

            f32x4 acc[6];
#pragma unroll
            for (int s = 0; s < 6; ++s) acc[s] = (f32x4){0.f, 0.f, 0.f, 0.f};
#pragma unroll
            for (int q = 0; q < 4; ++q)
#pragma unroll
                for (int s = 0; s < 6; ++s)
                    acc[s] = MFMA(af[q], bfrag[s][q], acc[s], 0, 0, 0);

            // select acc by row's o1, emission gather by row's o2 (R8 epilogue)
            float vals[4];
#pragma unroll
            for (int r = 0; r < 4; ++r) {
                const int o1 = (pk >> (8 * r)) & 15;
                const int o2 = (pk >> (8 * r + 4)) & 15;
                float v = acc[0][r];
                v = (o1 == 1) ? acc[1][r] : v;
                v = (o1 == 2) ? acc[2][r] : v;
                v = (o1 == 3) ? acc[3][r] : v;
                v = (o1 == 4) ? acc[4][r] : v;
                v = (o1 == 5) ? acc[5][r] : v;
                vals[r] = v * Bt[o2 * NS + cc];
            }

            ++ps;
            if ((ps & 15) == 0) {   // rescale (block-uniform branch)
#pragma unroll
                for (int r = 0; r < 4; ++r) {
                    float sm = vals[r];
#pragma unroll
                    for (int off = 1; off < 16; off <<= 1) sm += __shfl_xor(sm, off);
                    if (li == 0) part[w][4 * h + r] = sm;
                }
                __syncthreads();
                if (tid < ROWS) {
                    float Z = 0.f;
#pragma unroll
                    for (int ww = 0; ww < WAVES; ++ww) Z += part[ww][tid];
                    ll += logf(Z);
                    Zs[tid] = 1.0f / Z;
                }
                __syncthreads();
#pragma unroll
                for (int r = 0; r < 4; ++r) vals[r] *= Zs[4 * h + r];
            }

            // write alpha_new[4h+r][cc], swizzled bf16
#pragma unroll
            for (int r = 0; r < 4; ++r)
                alds[cur ^ 1][SWZ(4 * h + r, cc)] = f2bf(vals[r]);
            __syncthreads();
            cur ^= 1;
        }
    }

    // ---- final single step t = 8191: alpha @ A (Ct[6]), * e_{obs[b][8191]} ----
    {
        bf16x8 af[4];
#pragma unroll
        for (int q = 0; q < 4; ++q)
            af[q] = *(const bf16x8*)&alds[cur][SWZ(li, 32 * q + 8 * h)];
        f32x4 acc = (f32x4){0.f, 0.f, 0.f, 0.f};
#pragma unroll
        for (int q = 0; q < 4; ++q) acc = MFMA(af[q], afinB[q], acc, 0, 0, 0);
#pragma unroll
        for (int r = 0; r < 4; ++r) {
            const int o = obs_lds[4 * h + r][127];
            float sm = acc[r] * Bt[o * NS + cc];
#pragma unroll
            for (int off = 1; off < 16; off <<= 1) sm += __shfl_xor(sm, off);
            if (li == 0) part[w][4 * h + r] = sm;
        }
        __syncthreads();
        if (tid < ROWS) {
            float Z = 0.f;
#pragma unroll
            for (int ww = 0; ww < WAVES; ++ww) Z += part[ww][tid];
            out[brow0 + tid] = ll + logf(Z);
        }
    }
}

// ---------------------------------------------------------------------------
// Fallback (round-7 kernel) if workspace is too small for Ct.
// ---------------------------------------------------------------------------
__global__ void __launch_bounds__(256, 1)
hmm_gemm_kernel(const int* __restrict__ obs, const float* __restrict__ I,
                const float* __restrict__ A, const float* __restrict__ Bm,
                float* __restrict__ out)
{
    __shared__ __align__(16) ushort alds2[2][ROWS * NS];
    __shared__ float Bt[NE * NS];
    __shared__ __align__(16) int obs_lds[ROWS][132];
    __shared__ float part[4][ROWS];
    __shared__ float Zs[ROWS];

    const int tid = threadIdx.x;
    const int w   = tid >> 6;
    const int l   = tid & 63;
    const int h   = l >> 4;
    const int li  = l & 15;
    const int brow0 = blockIdx.x * ROWS;

    if (tid < NS) {
#pragma unroll
        for (int k = 0; k < NE; ++k) Bt[k * NS + tid] = Bm[tid * NE + k];
    }
    {
        const int r = tid >> 4, i0 = (tid & 15) * 8;
        const int32x4* g = (const int32x4*)(obs + (size_t)(brow0 + r) * NT + i0);
        *(int32x4*)&obs_lds[r][i0]     = g[0];
        *(int32x4*)&obs_lds[r][i0 + 4] = g[1];
    }
    bf16x8 bfrag[2][4];
#pragma unroll
    for (int tl = 0; tl < 2; ++tl) {
#pragma unroll
        for (int q = 0; q < 4; ++q) {
            const float* src = A + (size_t)(32 * q + 8 * h) * NS + (32 * w + 16 * tl + li);
            bf16x8 f;
#pragma unroll
            for (int j = 0; j < 8; ++j) f[j] = (short)f2bf(src[j * NS]);
            bfrag[tl][q] = f;
        }
    }
    __syncthreads();
    {
        const int r = tid >> 4, c0 = (tid & 15) * 8;
        const int o0 = obs_lds[r][0];
#pragma unroll
        for (int j = 0; j < 8; ++j) {
            const int c = c0 + j;
            alds2[0][SWZ(r, c)] = f2bf(I[c] * Bt[o0 * NS + c]);
        }
    }
    __syncthreads();

    float ll = 0.f;
    int cur = 0;
    for (int t = 1; t < NT; ++t) {
        if ((t & 127) == 0) {
            const int r = tid >> 4, i0 = (tid & 15) * 8;
            const int32x4* g = (const int32x4*)(obs + (size_t)(brow0 + r) * NT + t + i0);
            *(int32x4*)&obs_lds[r][i0]     = g[0];
            *(int32x4*)&obs_lds[r][i0 + 4] = g[1];
            __syncthreads();
        }
        bf16x8 af[4];
#pragma unroll
        for (int q = 0; q < 4; ++q)
            af[q] = *(const bf16x8*)&alds2[cur][SWZ(li, 32 * q + 8 * h)];
        const int tt = t & 127;
        int o[4];
#pragma unroll
        for (int r = 0; r < 4; ++r) o[r] = obs_lds[4 * h + r][tt];
        f32x4 acc[2];
        acc[0] = (f32x4){0.f, 0.f, 0.f, 0.f};
        acc[1] = (f32x4){0.f, 0.f, 0.f, 0.f};
#pragma unroll
        for (int q = 0; q < 4; ++q) {
            acc[0] = MFMA(af[q], bfrag[0][q], acc[0], 0, 0, 0);
            acc[1] = MFMA(af[q], bfrag[1][q], acc[1], 0, 0, 0);
        }
        float vals[2][4];
#pragma unroll
        for (int tl = 0; tl < 2; ++tl) {
            const int cidx = 32 * w + 16 * tl + li;
#pragma unroll
            for (int r = 0; r < 4; ++r) vals[tl][r] = acc[tl][r] * Bt[o[r] * NS + cidx];
        }
        const bool resc = ((t & 15) == 0) || (t == NT - 1);
        if (resc) {
#pragma unroll
            for (int r = 0; r < 4; ++r) {
                float s = vals[0][r] + vals[1][r];
#pragma unroll
                for (int off = 1; off < 16; off <<= 1) s += __shfl_xor(s, off);
                if (li == 0) part[w][4 * h + r] = s;
            }
            __syncthreads();
            if (tid < ROWS) {
                float Z = part[0][tid] + part[1][tid] + part[2][tid] + part[3][tid];
                ll += logf(Z);
                Zs[tid] = 1.0f / Z;
            }
            __syncthreads();
#pragma unroll
            for (int tl = 0; tl < 2; ++tl)
#pragma unroll
                for (int r = 0; r < 4; ++r) vals[tl][r] *= Zs[4 * h + r];
        }
#pragma unroll
        for (int tl = 0; tl < 2; ++tl) {
            const int cidx = 32 * w + 16 * tl + li;
#pragma unroll
            for (int r = 0; r < 4; ++r)
                alds2[cur ^ 1][SWZ(4 * h + r, cidx)] = f2bf(vals[tl][r]);
        }
        __syncthreads();
        cur ^= 1;
    }
    if (tid < ROWS) out[brow0 + tid] = ll;
}

extern "C" void kernel_launch(void* const* d_in, const int* in_sizes, int n_in,
                              void* d_out, int out_size, void* d_ws, size_t ws_size,
                              hipStream_t stream) {
    (void)in_sizes; (void)n_in; (void)out_size;
    const int*   obs = (const int*)d_in[0];
    const float* I   = (const float*)d_in[1];
    const float* A   = (const float*)d_in[2];
    const float* Bm  = (const float*)d_in[3];
    float*       out = (float*)d_out;

    if (ws_size < (size_t)CT_BYTES) {
        hipLaunchKernelGGL(hmm_gemm_kernel, dim3(NB / ROWS), dim3(256), 0, stream,
                           obs, I, A, Bm, out);
        return;
    }
    ushort* Ct = (ushort*)d_ws;
    hipLaunchKernelGGL(hmm_precompute_kernel, dim3(NMAT, 4), dim3(128), 0, stream,
                       A, Bm, Ct);
    hipLaunchKernelGGL(hmm_pair8_kernel, dim3(NB / ROWS), dim3(512), 0, stream,
                       obs, I, Bm, Ct, out);
}